// Round 3
// baseline (3831.799 us; speedup 1.0000x reference)
//
#include <hip/hip_runtime.h>
#include <hip/hip_bf16.h>

#define N_NODE 8000
#define EDGES  524288   // 2^19 per relation
#define LOG2E  19
#define NREL   4

// ---------------- degree kernels ----------------
__global__ void deg_kernel(const int* __restrict__ src, const int* __restrict__ dst,
                           float* __restrict__ deg_o, float* __restrict__ deg_i) {
    int t = blockIdx.x * blockDim.x + threadIdx.x;
    if (t >= NREL * EDGES) return;
    int r = t >> LOG2E;
    atomicAdd(&deg_o[r * N_NODE + src[t]], 1.0f);
    atomicAdd(&deg_i[r * N_NODE + dst[t]], 1.0f);
}

__global__ void rdeg_kernel(float* deg, int n) {
    int t = blockIdx.x * blockDim.x + threadIdx.x;
    if (t < n) deg[t] = rsqrtf(fmaxf(deg[t], 1.0f));
}

// ---------------- embed GEMM: C[M x 64] += A[M x K] @ W[K x 64] ----------------
// block tile 128x64, thread tile 8x4, KC=32, split-K with atomic reduce.
__global__ __launch_bounds__(256) void embed_gemm(
    const float* __restrict__ A, const float* __restrict__ W,
    float* __restrict__ C, int M, int K, int k_per_split) {
    __shared__ float sAT[32][132];  // A transposed: [k][row], pad 128->132
    __shared__ float sW[32][68];    // [k][col], pad 64->68
    const int tid = threadIdx.x;
    const int tx = tid & 15, ty = tid >> 4;
    const int row0 = blockIdx.x * 128;
    const int kb = blockIdx.y * k_per_split;
    const int ke = kb + k_per_split;
    float acc[8][4] = {};

    for (int kk0 = kb; kk0 < ke; kk0 += 32) {
        #pragma unroll
        for (int i = 0; i < 4; ++i) {
            int f = tid + i * 256;
            int r = f >> 3, k4 = f & 7;
            int row = min(row0 + r, M - 1);   // clamp; outputs predicated
            const float4 v = *(const float4*)(A + (size_t)row * K + kk0 + k4 * 4);
            sAT[k4 * 4 + 0][r] = v.x; sAT[k4 * 4 + 1][r] = v.y;
            sAT[k4 * 4 + 2][r] = v.z; sAT[k4 * 4 + 3][r] = v.w;
        }
        #pragma unroll
        for (int i = 0; i < 2; ++i) {
            int f = tid + i * 256;
            int kr = f >> 4, c4 = f & 15;
            *(float4*)&sW[kr][c4 * 4] = *(const float4*)(W + (size_t)(kk0 + kr) * 64 + c4 * 4);
        }
        __syncthreads();
        #pragma unroll
        for (int kk = 0; kk < 32; ++kk) {
            float4 a0 = *(const float4*)&sAT[kk][ty * 8];
            float4 a1 = *(const float4*)&sAT[kk][ty * 8 + 4];
            float4 w  = *(const float4*)&sW[kk][tx * 4];
            float av[8] = {a0.x, a0.y, a0.z, a0.w, a1.x, a1.y, a1.z, a1.w};
            float wv[4] = {w.x, w.y, w.z, w.w};
            #pragma unroll
            for (int i = 0; i < 8; ++i) {
                #pragma unroll
                for (int j = 0; j < 4; ++j)
                    acc[i][j] = fmaf(av[i], wv[j], acc[i][j]);
            }
        }
        __syncthreads();
    }
    #pragma unroll
    for (int i = 0; i < 8; ++i) {
        int row = row0 + ty * 8 + i;
        if (row < M) {
            #pragma unroll
            for (int j = 0; j < 4; ++j)
                atomicAdd(&C[(size_t)row * 64 + tx * 4 + j], acc[i][j]);
        }
    }
}

// ---------------- small GEMM: out[r] = diag(scale[r]) * A_r [M x K] @ W[r] [K x N] ----------------
template<int K, int N>
__global__ __launch_bounds__(256) void gemm_small(
    const float* __restrict__ Adrug, const float* __restrict__ Adis,
    const float* __restrict__ Wall, const float* __restrict__ scaleAll,
    float* __restrict__ outAll, int M) {
    const int r = blockIdx.y;
    const float* A = (r < 2) ? Adrug : Adis;
    const float* W = Wall + (size_t)r * K * N;
    const float* scale = scaleAll ? (scaleAll + (size_t)r * N_NODE) : nullptr;
    float* O = outAll + (size_t)r * M * N;

    __shared__ float sAT[K][68];      // [k][row], 64 rows
    __shared__ float sW[K][N + 4];
    const int tid = threadIdx.x;
    const int tx = tid & 15, ty = tid >> 4;
    const int row0 = blockIdx.x * 64;
    constexpr int NC = N / 16;

    constexpr int AF4 = 64 * K / 4 / 256;
    #pragma unroll
    for (int i = 0; i < AF4; ++i) {
        int f = tid + i * 256;
        int rr = f / (K / 4), k4 = f % (K / 4);
        int row = row0 + rr;
        float s = scale ? scale[row] : 1.0f;
        const float4 v = *(const float4*)(A + (size_t)row * K + k4 * 4);
        sAT[k4 * 4 + 0][rr] = v.x * s; sAT[k4 * 4 + 1][rr] = v.y * s;
        sAT[k4 * 4 + 2][rr] = v.z * s; sAT[k4 * 4 + 3][rr] = v.w * s;
    }
    constexpr int WF4 = K * N / 4 / 256;
    #pragma unroll
    for (int i = 0; i < WF4; ++i) {
        int f = tid + i * 256;
        int kr = f / (N / 4), c4 = f % (N / 4);
        *(float4*)&sW[kr][c4 * 4] = *(const float4*)(W + (size_t)kr * N + c4 * 4);
    }
    __syncthreads();

    float acc[4][NC] = {};
    #pragma unroll
    for (int kk = 0; kk < K; ++kk) {
        float4 a = *(const float4*)&sAT[kk][ty * 4];
        float av[4] = {a.x, a.y, a.z, a.w};
        float wv[NC];
        if constexpr (NC == 4) {
            float4 w = *(const float4*)&sW[kk][tx * 4];
            wv[0] = w.x; wv[1] = w.y; wv[2] = w.z; wv[3] = w.w;
        } else {
            float2 w = *(const float2*)&sW[kk][tx * 2];
            wv[0] = w.x; wv[1] = w.y;
        }
        #pragma unroll
        for (int i = 0; i < 4; ++i) {
            #pragma unroll
            for (int j = 0; j < NC; ++j)
                acc[i][j] = fmaf(av[i], wv[j], acc[i][j]);
        }
    }
    #pragma unroll
    for (int i = 0; i < 4; ++i) {
        int row = row0 + ty * 4 + i;
        if constexpr (NC == 4) {
            float4 v = {acc[i][0], acc[i][1], acc[i][2], acc[i][3]};
            *(float4*)(O + (size_t)row * N + tx * 4) = v;
        } else {
            float2 v = {acc[i][0], acc[i][1]};
            *(float2*)(O + (size_t)row * N + tx * 2) = v;
        }
    }
}

// ---------------- edge scatter: agg[r][dst] += m[r][src] ----------------
template<int N>
__global__ void scatter_kernel(const float* __restrict__ m, const int* __restrict__ src,
                               const int* __restrict__ dst, float* __restrict__ agg) {
    constexpr int NF4 = N / 4;
    int t = blockIdx.x * blockDim.x + threadIdx.x;
    int er = t / NF4;
    int f4 = t % NF4;
    if (er >= NREL * EDGES) return;
    int r = er >> LOG2E;
    int s = src[er], d = dst[er];
    const float4 v = *(const float4*)(m + ((size_t)r * N_NODE + s) * N + f4 * 4);
    float* ap = agg + ((size_t)r * N_NODE + d) * N + f4 * 4;
    atomicAdd(ap + 0, v.x); atomicAdd(ap + 1, v.y);
    atomicAdd(ap + 2, v.z); atomicAdd(ap + 3, v.w);
}

// ---------------- combine: relu(agg[ra]*rdeg_i[ra] + agg[rb]*rdeg_i[rb] + b[ra] + b[rb]) ----------------
template<int N>
__global__ void combine_kernel(const float* __restrict__ agg, const float* __restrict__ rdeg_i,
                               const float* __restrict__ b, float* __restrict__ outDrug,
                               float* __restrict__ outDis) {
    int t = blockIdx.x * blockDim.x + threadIdx.x;
    if (t >= N_NODE * N) return;
    int i = t / N, f = t % N;
    int typ = blockIdx.y;                       // 0: drug (rel 0,2)  1: dis (rel 1,3)
    int ra = typ == 0 ? 0 : 1, rb = typ == 0 ? 2 : 3;
    float va = agg[((size_t)ra * N_NODE + i) * N + f] * rdeg_i[ra * N_NODE + i];
    float vb = agg[((size_t)rb * N_NODE + i) * N + f] * rdeg_i[rb * N_NODE + i];
    float v = fmaxf(va + vb + b[ra * N + f] + b[rb * N + f], 0.0f);
    (typ == 0 ? outDrug : outDis)[t] = v;
}

// ---------------- final NT GEMM: C[M x Nc] = A[M x 32] @ B[Nc x 32]^T ----------------
__global__ __launch_bounds__(256) void gemm_nt_final(
    const float* __restrict__ A, const float* __restrict__ B,
    float* __restrict__ C, int M, int Nc) {
    __shared__ float sAT[32][132];
    __shared__ float sBT[32][68];
    const int tid = threadIdx.x;
    const int tx = tid & 15, ty = tid >> 4;
    const int row0 = blockIdx.x * 128, col0 = blockIdx.y * 64;
    #pragma unroll
    for (int i = 0; i < 4; ++i) {
        int f = tid + i * 256;
        int r = f >> 3, k4 = f & 7;
        int row = min(row0 + r, M - 1);
        const float4 v = *(const float4*)(A + (size_t)row * 32 + k4 * 4);
        sAT[k4 * 4 + 0][r] = v.x; sAT[k4 * 4 + 1][r] = v.y;
        sAT[k4 * 4 + 2][r] = v.z; sAT[k4 * 4 + 3][r] = v.w;
    }
    #pragma unroll
    for (int i = 0; i < 2; ++i) {
        int f = tid + i * 256;
        int br = f >> 3, k4 = f & 7;
        const float4 v = *(const float4*)(B + (size_t)(col0 + br) * 32 + k4 * 4);
        sBT[k4 * 4 + 0][br] = v.x; sBT[k4 * 4 + 1][br] = v.y;
        sBT[k4 * 4 + 2][br] = v.z; sBT[k4 * 4 + 3][br] = v.w;
    }
    __syncthreads();
    float acc[8][4] = {};
    #pragma unroll
    for (int a = 0; a < 32; ++a) {
        float4 a0 = *(const float4*)&sAT[a][ty * 8];
        float4 a1 = *(const float4*)&sAT[a][ty * 8 + 4];
        float4 b4 = *(const float4*)&sBT[a][tx * 4];
        float av[8] = {a0.x, a0.y, a0.z, a0.w, a1.x, a1.y, a1.z, a1.w};
        float bv[4] = {b4.x, b4.y, b4.z, b4.w};
        #pragma unroll
        for (int i = 0; i < 8; ++i) {
            #pragma unroll
            for (int j = 0; j < 4; ++j)
                acc[i][j] = fmaf(av[i], bv[j], acc[i][j]);
        }
    }
    #pragma unroll
    for (int i = 0; i < 8; ++i) {
        int row = row0 + ty * 8 + i;
        if (row < M) {
            float4 v = {acc[i][0], acc[i][1], acc[i][2], acc[i][3]};
            *(float4*)(C + (size_t)row * Nc + col0 + tx * 4) = v;
        }
    }
}

extern "C" void kernel_launch(void* const* d_in, const int* in_sizes, int n_in,
                              void* d_out, int out_size, void* d_ws, size_t ws_size,
                              hipStream_t stream) {
    const float* feat_drug = (const float*)d_in[0];
    const float* feat_dis  = (const float*)d_in[1];
    const float* W_drug    = (const float*)d_in[2];
    const float* W_dis     = (const float*)d_in[3];
    const float* W1        = (const float*)d_in[4];
    const float* b1        = (const float*)d_in[5];
    const float* W2        = (const float*)d_in[6];
    const float* b2        = (const float*)d_in[7];
    const float* Wf        = (const float*)d_in[8];
    const int*   src       = (const int*)d_in[9];
    const int*   dst       = (const int*)d_in[10];
    float* out = (float*)d_out;
    float* ws  = (float*)d_ws;

    // Workspace layout (floats), total 5,184,000 = 20.7 MB, with safe aliasing:
    //   h1 reuses h_drug/h_dis (dead after layer-1 gemm_small reads them);
    //   h2 and g live inside m's region (m dead after layer-2 scatter).
    float* rdeg_o  = ws;                 // 4*8000
    float* rdeg_i  = rdeg_o + 32000;     // 4*8000
    float* h_drug  = ws + 64000;         // 8000*64
    float* h_dis   = h_drug + 512000;    // 8000*64
    float* m       = ws + 1088000;       // 4*8000*64
    float* agg     = m + 2048000;        // 4*8000*64  (end: 5,184,000 floats)
    float* h1_drug = h_drug;             // alias: h_drug dead after L1 gemm_small
    float* h1_dis  = h_dis;              // alias
    float* h2_drug = m;                  // alias: m dead after L2 scatter
    float* h2_dis  = m + 256000;         // alias
    float* g       = m + 512000;         // alias

    // zero degree counters and split-K accumulation targets
    hipMemsetAsync(rdeg_o, 0, 64000 * sizeof(float), stream);     // rdeg_o + rdeg_i
    hipMemsetAsync(h_drug, 0, 1024000 * sizeof(float), stream);   // h_drug + h_dis

    deg_kernel<<<(NREL * EDGES + 255) / 256, 256, 0, stream>>>(src, dst, rdeg_o, rdeg_i);
    rdeg_kernel<<<(64000 + 255) / 256, 256, 0, stream>>>(rdeg_o, 64000);

    // input embeddings: h = feat @ W   (split-K x25 -> 63*25=1575 blocks)
    dim3 ge(63, 25);
    embed_gemm<<<ge, 256, 0, stream>>>(feat_drug, W_drug, h_drug, N_NODE, N_NODE, 320);
    embed_gemm<<<ge, 256, 0, stream>>>(feat_dis,  W_dis,  h_dis,  N_NODE, N_NODE, 320);

    // ---- hetero layer 1 (64 -> 64) ----
    gemm_small<64, 64><<<dim3(125, 4), 256, 0, stream>>>(h_drug, h_dis, W1, rdeg_o, m, N_NODE);
    hipMemsetAsync(agg, 0, 2048000 * sizeof(float), stream);
    scatter_kernel<64><<<(NREL * EDGES * 16) / 256, 256, 0, stream>>>(m, src, dst, agg);
    combine_kernel<64><<<dim3((N_NODE * 64) / 256, 2), 256, 0, stream>>>(agg, rdeg_i, b1, h1_drug, h1_dis);

    // ---- hetero layer 2 (64 -> 32) ----
    gemm_small<64, 32><<<dim3(125, 4), 256, 0, stream>>>(h1_drug, h1_dis, W2, rdeg_o, m, N_NODE);
    hipMemsetAsync(agg, 0, 1024000 * sizeof(float), stream);
    scatter_kernel<32><<<(NREL * EDGES * 8) / 256, 256, 0, stream>>>(m, src, dst, agg);
    combine_kernel<32><<<dim3((N_NODE * 32) / 256, 2), 256, 0, stream>>>(agg, rdeg_i, b2, h2_drug, h2_dis);

    // ---- bilinear scoring: out = h2_drug @ (h2_dis @ Wf)^T ----
    gemm_small<32, 32><<<dim3(125, 1), 256, 0, stream>>>(h2_dis, h2_dis, Wf, nullptr, g, N_NODE);
    gemm_nt_final<<<dim3(63, 125), 256, 0, stream>>>(h2_drug, g, out, N_NODE, N_NODE);
}

// Round 5
// 1384.789 us; speedup vs baseline: 2.7671x; 2.7671x over previous
//
#include <hip/hip_runtime.h>
#include <hip/hip_bf16.h>

#define N_NODE 8000
#define EDGES  524288   // 2^19 per relation
#define LOG2E  19
#define NREL   4

// ---------------- CSR build: count, rdeg, scan, place ----------------
__global__ void count_kernel(const int* __restrict__ src, const int* __restrict__ dst,
                             int* __restrict__ cnt_o, int* __restrict__ cnt_i) {
    int t = blockIdx.x * blockDim.x + threadIdx.x;
    if (t >= NREL * EDGES) return;
    int r = t >> LOG2E;
    atomicAdd(&cnt_o[r * N_NODE + src[t]], 1);
    atomicAdd(&cnt_i[r * N_NODE + dst[t]], 1);
}

__global__ void rdeg_kernel(const int* __restrict__ cnt, float* __restrict__ rdeg, int n) {
    int t = blockIdx.x * blockDim.x + threadIdx.x;
    if (t < n) rdeg[t] = rsqrtf((float)max(cnt[t], 1));
}

// exclusive prefix sum over 32000 counters; single block of 1024, 32 chunks.
__global__ __launch_bounds__(1024) void scan_kernel(const int* __restrict__ cnt,
                                                    int* __restrict__ off, int* __restrict__ cursor) {
    __shared__ int buf[1024];
    __shared__ int sbase;
    if (threadIdx.x == 0) sbase = 0;
    __syncthreads();
    for (int c = 0; c < 32; ++c) {
        int i = c * 1024 + threadIdx.x;
        int v = (i < NREL * N_NODE) ? cnt[i] : 0;
        buf[threadIdx.x] = v;
        __syncthreads();
        for (int s = 1; s < 1024; s <<= 1) {
            int t = (threadIdx.x >= s) ? buf[threadIdx.x - s] : 0;
            __syncthreads();
            buf[threadIdx.x] += t;
            __syncthreads();
        }
        int b = sbase;
        if (i < NREL * N_NODE) {
            int excl = b + buf[threadIdx.x] - v;
            off[i] = excl;
            cursor[i] = excl;
        }
        __syncthreads();
        if (threadIdx.x == 1023) sbase = b + buf[1023];
        __syncthreads();
    }
}

__global__ void place_kernel(const int* __restrict__ src, const int* __restrict__ dst,
                             int* __restrict__ cursor, unsigned short* __restrict__ csr) {
    int t = blockIdx.x * blockDim.x + threadIdx.x;
    if (t >= NREL * EDGES) return;
    int r = t >> LOG2E;
    int pos = atomicAdd(&cursor[r * N_NODE + dst[t]], 1);
    csr[pos] = (unsigned short)src[t];
}

// ---------------- embed GEMM: C[M x 64] += A[M x K] @ W[K x 64] ----------------
__global__ __launch_bounds__(256) void embed_gemm(
    const float* __restrict__ A, const float* __restrict__ W,
    float* __restrict__ C, int M, int K, int k_per_split) {
    __shared__ float sAT[32][132];
    __shared__ float sW[32][68];
    const int tid = threadIdx.x;
    const int tx = tid & 15, ty = tid >> 4;
    const int row0 = blockIdx.x * 128;
    const int kb = blockIdx.y * k_per_split;
    const int ke = kb + k_per_split;
    float acc[8][4] = {};

    for (int kk0 = kb; kk0 < ke; kk0 += 32) {
        #pragma unroll
        for (int i = 0; i < 4; ++i) {
            int f = tid + i * 256;
            int r = f >> 3, k4 = f & 7;
            int row = min(row0 + r, M - 1);
            const float4 v = *(const float4*)(A + (size_t)row * K + kk0 + k4 * 4);
            sAT[k4 * 4 + 0][r] = v.x; sAT[k4 * 4 + 1][r] = v.y;
            sAT[k4 * 4 + 2][r] = v.z; sAT[k4 * 4 + 3][r] = v.w;
        }
        #pragma unroll
        for (int i = 0; i < 2; ++i) {
            int f = tid + i * 256;
            int kr = f >> 4, c4 = f & 15;
            *(float4*)&sW[kr][c4 * 4] = *(const float4*)(W + (size_t)(kk0 + kr) * 64 + c4 * 4);
        }
        __syncthreads();
        #pragma unroll
        for (int kk = 0; kk < 32; ++kk) {
            float4 a0 = *(const float4*)&sAT[kk][ty * 8];
            float4 a1 = *(const float4*)&sAT[kk][ty * 8 + 4];
            float4 w  = *(const float4*)&sW[kk][tx * 4];
            float av[8] = {a0.x, a0.y, a0.z, a0.w, a1.x, a1.y, a1.z, a1.w};
            float wv[4] = {w.x, w.y, w.z, w.w};
            #pragma unroll
            for (int i = 0; i < 8; ++i) {
                #pragma unroll
                for (int j = 0; j < 4; ++j)
                    acc[i][j] = fmaf(av[i], wv[j], acc[i][j]);
            }
        }
        __syncthreads();
    }
    #pragma unroll
    for (int i = 0; i < 8; ++i) {
        int row = row0 + ty * 8 + i;
        if (row < M) {
            #pragma unroll
            for (int j = 0; j < 4; ++j)
                atomicAdd(&C[(size_t)row * 64 + tx * 4 + j], acc[i][j]);
        }
    }
}

// ---------------- small GEMM: out[r] = diag(scale[r]) * A_r [M x K] @ W[r] [K x N] ----------------
template<int K, int N>
__global__ __launch_bounds__(256) void gemm_small(
    const float* __restrict__ Adrug, const float* __restrict__ Adis,
    const float* __restrict__ Wall, const float* __restrict__ scaleAll,
    float* __restrict__ outAll, int M) {
    const int r = blockIdx.y;
    const float* A = (r < 2) ? Adrug : Adis;
    const float* W = Wall + (size_t)r * K * N;
    const float* scale = scaleAll ? (scaleAll + (size_t)r * N_NODE) : nullptr;
    float* O = outAll + (size_t)r * M * N;

    __shared__ float sAT[K][68];
    __shared__ float sW[K][N + 4];
    const int tid = threadIdx.x;
    const int tx = tid & 15, ty = tid >> 4;
    const int row0 = blockIdx.x * 64;
    constexpr int NC = N / 16;

    constexpr int AF4 = 64 * K / 4 / 256;
    #pragma unroll
    for (int i = 0; i < AF4; ++i) {
        int f = tid + i * 256;
        int rr = f / (K / 4), k4 = f % (K / 4);
        int row = row0 + rr;
        float s = scale ? scale[row] : 1.0f;
        const float4 v = *(const float4*)(A + (size_t)row * K + k4 * 4);
        sAT[k4 * 4 + 0][rr] = v.x * s; sAT[k4 * 4 + 1][rr] = v.y * s;
        sAT[k4 * 4 + 2][rr] = v.z * s; sAT[k4 * 4 + 3][rr] = v.w * s;
    }
    constexpr int WF4 = K * N / 4 / 256;
    #pragma unroll
    for (int i = 0; i < WF4; ++i) {
        int f = tid + i * 256;
        int kr = f / (N / 4), c4 = f % (N / 4);
        *(float4*)&sW[kr][c4 * 4] = *(const float4*)(W + (size_t)kr * N + c4 * 4);
    }
    __syncthreads();

    float acc[4][NC] = {};
    #pragma unroll
    for (int kk = 0; kk < K; ++kk) {
        float4 a = *(const float4*)&sAT[kk][ty * 4];
        float av[4] = {a.x, a.y, a.z, a.w};
        float wv[NC];
        if constexpr (NC == 4) {
            float4 w = *(const float4*)&sW[kk][tx * 4];
            wv[0] = w.x; wv[1] = w.y; wv[2] = w.z; wv[3] = w.w;
        } else {
            float2 w = *(const float2*)&sW[kk][tx * 2];
            wv[0] = w.x; wv[1] = w.y;
        }
        #pragma unroll
        for (int i = 0; i < 4; ++i) {
            #pragma unroll
            for (int j = 0; j < NC; ++j)
                acc[i][j] = fmaf(av[i], wv[j], acc[i][j]);
        }
    }
    #pragma unroll
    for (int i = 0; i < 4; ++i) {
        int row = row0 + ty * 4 + i;
        if constexpr (NC == 4) {
            float4 v = {acc[i][0], acc[i][1], acc[i][2], acc[i][3]};
            *(float4*)(O + (size_t)row * N + tx * 4) = v;
        } else {
            float2 v = {acc[i][0], acc[i][1]};
            *(float2*)(O + (size_t)row * N + tx * 2) = v;
        }
    }
}

// ---------------- fused gather + norm + bias + relu ----------------
template<int N>
__global__ __launch_bounds__(256) void gather_combine(
    const float* __restrict__ m, const unsigned short* __restrict__ csr,
    const int* __restrict__ off, const int* __restrict__ cnt,
    const float* __restrict__ rdeg_i, const float* __restrict__ bias,
    float* __restrict__ outDrug, float* __restrict__ outDis) {
    constexpr int NPW = 64 / N;              // nodes per wave
    const int lane = threadIdx.x & 63;
    const int wave = threadIdx.x >> 6;
    const int sub = lane / N;
    const int f = lane % N;
    const int node = (blockIdx.x * 4 + wave) * NPW + sub;
    if (node >= N_NODE) return;
    const int typ = blockIdx.y;              // 0: drug (rel 0,2)  1: dis (rel 1,3)
    const int ra = (typ == 0) ? 0 : 1, rb = (typ == 0) ? 2 : 3;

    float acc[2] = {0.0f, 0.0f};
    const int rels[2] = {ra, rb};
    #pragma unroll
    for (int q = 0; q < 2; ++q) {
        const int rid = rels[q] * N_NODE + node;
        const int beg = off[rid];
        const int c = cnt[rid];
        const float* mr = m + (size_t)rels[q] * N_NODE * N;
        int k = 0;
        for (; k + 4 <= c; k += 4) {
            int s0 = csr[beg + k], s1 = csr[beg + k + 1];
            int s2 = csr[beg + k + 2], s3 = csr[beg + k + 3];
            float v0 = mr[s0 * N + f], v1 = mr[s1 * N + f];
            float v2 = mr[s2 * N + f], v3 = mr[s3 * N + f];
            acc[q] += (v0 + v1) + (v2 + v3);
        }
        for (; k < c; ++k) acc[q] += mr[csr[beg + k] * N + f];
    }
    float o = acc[0] * rdeg_i[ra * N_NODE + node] + acc[1] * rdeg_i[rb * N_NODE + node]
            + bias[ra * N + f] + bias[rb * N + f];
    o = fmaxf(o, 0.0f);
    (typ == 0 ? outDrug : outDis)[(size_t)node * N + f] = o;
}

// ---------------- final NT GEMM: C[M x Nc] = A[M x 32] @ B[Nc x 32]^T ----------------
__global__ __launch_bounds__(256) void gemm_nt_final(
    const float* __restrict__ A, const float* __restrict__ B,
    float* __restrict__ C, int M, int Nc) {
    __shared__ float sAT[32][132];
    __shared__ float sBT[32][68];
    const int tid = threadIdx.x;
    const int tx = tid & 15, ty = tid >> 4;
    const int row0 = blockIdx.x * 128, col0 = blockIdx.y * 64;
    #pragma unroll
    for (int i = 0; i < 4; ++i) {
        int f = tid + i * 256;
        int r = f >> 3, k4 = f & 7;
        int row = min(row0 + r, M - 1);
        const float4 v = *(const float4*)(A + (size_t)row * 32 + k4 * 4);
        sAT[k4 * 4 + 0][r] = v.x; sAT[k4 * 4 + 1][r] = v.y;
        sAT[k4 * 4 + 2][r] = v.z; sAT[k4 * 4 + 3][r] = v.w;
    }
    #pragma unroll
    for (int i = 0; i < 2; ++i) {
        int f = tid + i * 256;
        int br = f >> 3, k4 = f & 7;
        const float4 v = *(const float4*)(B + (size_t)(col0 + br) * 32 + k4 * 4);
        sBT[k4 * 4 + 0][br] = v.x; sBT[k4 * 4 + 1][br] = v.y;
        sBT[k4 * 4 + 2][br] = v.z; sBT[k4 * 4 + 3][br] = v.w;
    }
    __syncthreads();
    float acc[8][4] = {};
    #pragma unroll
    for (int a = 0; a < 32; ++a) {
        float4 a0 = *(const float4*)&sAT[a][ty * 8];
        float4 a1 = *(const float4*)&sAT[a][ty * 8 + 4];
        float4 b4 = *(const float4*)&sBT[a][tx * 4];
        float av[8] = {a0.x, a0.y, a0.z, a0.w, a1.x, a1.y, a1.z, a1.w};
        float bv[4] = {b4.x, b4.y, b4.z, b4.w};
        #pragma unroll
        for (int i = 0; i < 8; ++i) {
            #pragma unroll
            for (int j = 0; j < 4; ++j)
                acc[i][j] = fmaf(av[i], bv[j], acc[i][j]);
        }
    }
    #pragma unroll
    for (int i = 0; i < 8; ++i) {
        int row = row0 + ty * 8 + i;
        if (row < M) {
            float4 v = {acc[i][0], acc[i][1], acc[i][2], acc[i][3]};
            *(float4*)(C + (size_t)row * Nc + col0 + tx * 4) = v;
        }
    }
}

extern "C" void kernel_launch(void* const* d_in, const int* in_sizes, int n_in,
                              void* d_out, int out_size, void* d_ws, size_t ws_size,
                              hipStream_t stream) {
    const float* feat_drug = (const float*)d_in[0];
    const float* feat_dis  = (const float*)d_in[1];
    const float* W_drug    = (const float*)d_in[2];
    const float* W_dis     = (const float*)d_in[3];
    const float* W1        = (const float*)d_in[4];
    const float* b1        = (const float*)d_in[5];
    const float* W2        = (const float*)d_in[6];
    const float* b2        = (const float*)d_in[7];
    const float* Wf        = (const float*)d_in[8];
    const int*   src       = (const int*)d_in[9];
    const int*   dst       = (const int*)d_in[10];
    float* out = (float*)d_out;

    // ---- workspace carve: 20,322,304 B = 20.32 MB (< 20.74 MB proven in R3) ----
    float* fbase   = (float*)d_ws;
    float* rdeg_o  = fbase;                  // 32000
    float* rdeg_i  = fbase + 32000;          // 32000
    float* h_drug  = fbase + 64000;          // 8000*64
    float* h_dis   = fbase + 576000;         // 8000*64
    float* m       = fbase + 1088000;        // 4*8000*64
    float* h2_drug = fbase + 3136000;        // 8000*32
    float* h2_dis  = fbase + 3392000;        // 8000*32
    float* g       = fbase + 3648000;        // 8000*32  (floats end at 3,904,000)
    int*   ibase   = (int*)(fbase + 3904000);
    int*   cnt_o   = ibase;                  // 32000
    int*   cnt_i   = ibase + 32000;          // 32000
    int*   off     = ibase + 64000;          // 32000
    int*   cursor  = ibase + 96000;          // 32000
    unsigned short* csr = (unsigned short*)(ibase + 128000);   // 2,097,152 ushorts
    float* h1_drug = h_drug;                 // alias: h dead after L1 gemm_small
    float* h1_dis  = h_dis;                  // alias

    hipMemsetAsync(cnt_o, 0, 64000 * sizeof(int), stream);        // cnt_o + cnt_i
    hipMemsetAsync(h_drug, 0, 1024000 * sizeof(float), stream);   // split-K accumulators

    // ---- CSR build (dst-sorted, reused by both layers) ----
    count_kernel<<<8192, 256, 0, stream>>>(src, dst, cnt_o, cnt_i);
    rdeg_kernel<<<125, 256, 0, stream>>>(cnt_o, rdeg_o, 32000);
    rdeg_kernel<<<125, 256, 0, stream>>>(cnt_i, rdeg_i, 32000);
    scan_kernel<<<1, 1024, 0, stream>>>(cnt_i, off, cursor);
    place_kernel<<<8192, 256, 0, stream>>>(src, dst, cursor, csr);

    // ---- input embeddings: h = feat @ W (split-K x25) ----
    dim3 ge(63, 25);
    embed_gemm<<<ge, 256, 0, stream>>>(feat_drug, W_drug, h_drug, N_NODE, N_NODE, 320);
    embed_gemm<<<ge, 256, 0, stream>>>(feat_dis,  W_dis,  h_dis,  N_NODE, N_NODE, 320);

    // ---- hetero layer 1 (64 -> 64) ----
    gemm_small<64, 64><<<dim3(125, 4), 256, 0, stream>>>(h_drug, h_dis, W1, rdeg_o, m, N_NODE);
    gather_combine<64><<<dim3(2000, 2), 256, 0, stream>>>(m, csr, off, cnt_i, rdeg_i, b1, h1_drug, h1_dis);

    // ---- hetero layer 2 (64 -> 32) ----
    gemm_small<64, 32><<<dim3(125, 4), 256, 0, stream>>>(h1_drug, h1_dis, W2, rdeg_o, m, N_NODE);
    gather_combine<32><<<dim3(1000, 2), 256, 0, stream>>>(m, csr, off, cnt_i, rdeg_i, b2, h2_drug, h2_dis);

    // ---- bilinear scoring: out = h2_drug @ (h2_dis @ Wf)^T ----
    gemm_small<32, 32><<<dim3(125, 1), 256, 0, stream>>>(h2_dis, h2_dis, Wf, nullptr, g, N_NODE);
    gemm_nt_final<<<dim3(63, 125), 256, 0, stream>>>(h2_drug, g, out, N_NODE, N_NODE);
}

// Round 6
// 1252.776 us; speedup vs baseline: 3.0586x; 1.1054x over previous
//
#include <hip/hip_runtime.h>
#include <hip/hip_bf16.h>

#define N_NODE 8000
#define EDGES  524288   // 2^19 per relation
#define LOG2E  19
#define NREL   4

// ---------------- CSR build: count, rdeg, scan, place ----------------
__global__ void count_kernel(const int* __restrict__ src, const int* __restrict__ dst,
                             int* __restrict__ cnt_o, int* __restrict__ cnt_i) {
    int t = blockIdx.x * blockDim.x + threadIdx.x;
    if (t >= NREL * EDGES) return;
    int r = t >> LOG2E;
    atomicAdd(&cnt_o[r * N_NODE + src[t]], 1);
    atomicAdd(&cnt_i[r * N_NODE + dst[t]], 1);
}

__global__ void rdeg_kernel(const int* __restrict__ cnt, float* __restrict__ rdeg, int n) {
    int t = blockIdx.x * blockDim.x + threadIdx.x;
    if (t < n) rdeg[t] = rsqrtf((float)max(cnt[t], 1));
}

// exclusive prefix sum over 32000 counters; single block of 1024, 32 chunks.
__global__ __launch_bounds__(1024) void scan_kernel(const int* __restrict__ cnt,
                                                    int* __restrict__ off, int* __restrict__ cursor) {
    __shared__ int buf[1024];
    __shared__ int sbase;
    if (threadIdx.x == 0) sbase = 0;
    __syncthreads();
    for (int c = 0; c < 32; ++c) {
        int i = c * 1024 + threadIdx.x;
        int v = (i < NREL * N_NODE) ? cnt[i] : 0;
        buf[threadIdx.x] = v;
        __syncthreads();
        for (int s = 1; s < 1024; s <<= 1) {
            int t = (threadIdx.x >= s) ? buf[threadIdx.x - s] : 0;
            __syncthreads();
            buf[threadIdx.x] += t;
            __syncthreads();
        }
        int b = sbase;
        if (i < NREL * N_NODE) {
            int excl = b + buf[threadIdx.x] - v;
            off[i] = excl;
            cursor[i] = excl;
        }
        __syncthreads();
        if (threadIdx.x == 1023) sbase = b + buf[1023];
        __syncthreads();
    }
}

__global__ void place_kernel(const int* __restrict__ src, const int* __restrict__ dst,
                             int* __restrict__ cursor, unsigned short* __restrict__ csr) {
    int t = blockIdx.x * blockDim.x + threadIdx.x;
    if (t >= NREL * EDGES) return;
    int r = t >> LOG2E;
    int pos = atomicAdd(&cursor[r * N_NODE + dst[t]], 1);
    csr[pos] = (unsigned short)src[t];
}

// ---------------- embed GEMM: C[8000 x 64] += A[8000 x 8000] @ W[8000 x 64] ----------------
// 64-row tiles (125 row-blocks, exact), 5-way split-K (1600 k = 50 tiles of 32),
// register-prefetch pipeline, row-major A in LDS (no transpose), 4x4 thread tile.
__global__ __launch_bounds__(256) void embed_gemm(
    const float* __restrict__ A, const float* __restrict__ W,
    float* __restrict__ C, int K, int k_per_split) {
    __shared__ float sA[64][36];   // row-major, pad 32->36 (rows stay 16B-aligned)
    __shared__ float sW[32][68];   // [k][col], pad 64->68
    const int tid = threadIdx.x;
    const int tx = tid & 15, ty = tid >> 4;       // col-quad (16), row-quad (16)
    const int row0 = blockIdx.x * 64;
    const int kb = blockIdx.y * k_per_split;
    const int nt = k_per_split / 32;              // 50

    // staging indices: A 64x32 = 512 float4 (2/thread), W 32x64 = 512 float4 (2/thread)
    const int ar = tid >> 3, ak4 = tid & 7;       // A: rows ar, ar+32; k-quad ak4
    const int wk = tid >> 4, wc4 = tid & 15;      // W: k-rows wk, wk+16; col-quad wc4
    const float* Ap0 = A + (size_t)(row0 + ar) * K + ak4 * 4;
    const float* Ap1 = A + (size_t)(row0 + ar + 32) * K + ak4 * 4;
    const float* Wp0 = W + (size_t)wk * 64 + wc4 * 4;
    const float* Wp1 = W + (size_t)(wk + 16) * 64 + wc4 * 4;

    float4 pa0, pa1, pw0, pw1;
    // prologue: load tile 0
    pa0 = *(const float4*)(Ap0 + kb);
    pa1 = *(const float4*)(Ap1 + kb);
    pw0 = *(const float4*)(Wp0 + (size_t)kb * 64);
    pw1 = *(const float4*)(Wp1 + (size_t)kb * 64);

    float acc[4][4] = {};

    for (int t = 0; t < nt; ++t) {
        // regs -> LDS
        *(float4*)&sA[ar][ak4 * 4] = pa0;
        *(float4*)&sA[ar + 32][ak4 * 4] = pa1;
        *(float4*)&sW[wk][wc4 * 4] = pw0;
        *(float4*)&sW[wk + 16][wc4 * 4] = pw1;
        __syncthreads();
        // issue next tile's global loads (latency hides under compute)
        if (t + 1 < nt) {
            int kk0 = kb + (t + 1) * 32;
            pa0 = *(const float4*)(Ap0 + kk0);
            pa1 = *(const float4*)(Ap1 + kk0);
            pw0 = *(const float4*)(Wp0 + (size_t)kk0 * 64);
            pw1 = *(const float4*)(Wp1 + (size_t)kk0 * 64);
        }
        // compute 32 k-steps
        #pragma unroll
        for (int q = 0; q < 8; ++q) {           // 8 quads of 4 k
            float4 a0 = *(const float4*)&sA[ty * 4 + 0][q * 4];
            float4 a1 = *(const float4*)&sA[ty * 4 + 1][q * 4];
            float4 a2 = *(const float4*)&sA[ty * 4 + 2][q * 4];
            float4 a3 = *(const float4*)&sA[ty * 4 + 3][q * 4];
            float4 w0 = *(const float4*)&sW[q * 4 + 0][tx * 4];
            float4 w1 = *(const float4*)&sW[q * 4 + 1][tx * 4];
            float4 w2 = *(const float4*)&sW[q * 4 + 2][tx * 4];
            float4 w3 = *(const float4*)&sW[q * 4 + 3][tx * 4];
            float av[4][4] = {{a0.x, a0.y, a0.z, a0.w}, {a1.x, a1.y, a1.z, a1.w},
                              {a2.x, a2.y, a2.z, a2.w}, {a3.x, a3.y, a3.z, a3.w}};
            float wv[4][4] = {{w0.x, w0.y, w0.z, w0.w}, {w1.x, w1.y, w1.z, w1.w},
                              {w2.x, w2.y, w2.z, w2.w}, {w3.x, w3.y, w3.z, w3.w}};
            #pragma unroll
            for (int i = 0; i < 4; ++i) {
                #pragma unroll
                for (int j = 0; j < 4; ++j) {
                    #pragma unroll
                    for (int kk = 0; kk < 4; ++kk)
                        acc[i][j] = fmaf(av[i][kk], wv[kk][j], acc[i][j]);
                }
            }
        }
        __syncthreads();
    }
    #pragma unroll
    for (int i = 0; i < 4; ++i) {
        float* cp = &C[(size_t)(row0 + ty * 4 + i) * 64 + tx * 4];
        #pragma unroll
        for (int j = 0; j < 4; ++j)
            atomicAdd(cp + j, acc[i][j]);
    }
}

// ---------------- small GEMM: out[r] = diag(scale[r]) * A_r [M x K] @ W[r] [K x N] ----------------
template<int K, int N>
__global__ __launch_bounds__(256) void gemm_small(
    const float* __restrict__ Adrug, const float* __restrict__ Adis,
    const float* __restrict__ Wall, const float* __restrict__ scaleAll,
    float* __restrict__ outAll, int M) {
    const int r = blockIdx.y;
    const float* A = (r < 2) ? Adrug : Adis;
    const float* W = Wall + (size_t)r * K * N;
    const float* scale = scaleAll ? (scaleAll + (size_t)r * N_NODE) : nullptr;
    float* O = outAll + (size_t)r * M * N;

    __shared__ float sAT[K][68];
    __shared__ float sW[K][N + 4];
    const int tid = threadIdx.x;
    const int tx = tid & 15, ty = tid >> 4;
    const int row0 = blockIdx.x * 64;
    constexpr int NC = N / 16;

    constexpr int AF4 = 64 * K / 4 / 256;
    #pragma unroll
    for (int i = 0; i < AF4; ++i) {
        int f = tid + i * 256;
        int rr = f / (K / 4), k4 = f % (K / 4);
        int row = row0 + rr;
        float s = scale ? scale[row] : 1.0f;
        const float4 v = *(const float4*)(A + (size_t)row * K + k4 * 4);
        sAT[k4 * 4 + 0][rr] = v.x * s; sAT[k4 * 4 + 1][rr] = v.y * s;
        sAT[k4 * 4 + 2][rr] = v.z * s; sAT[k4 * 4 + 3][rr] = v.w * s;
    }
    constexpr int WF4 = K * N / 4 / 256;
    #pragma unroll
    for (int i = 0; i < WF4; ++i) {
        int f = tid + i * 256;
        int kr = f / (N / 4), c4 = f % (N / 4);
        *(float4*)&sW[kr][c4 * 4] = *(const float4*)(W + (size_t)kr * N + c4 * 4);
    }
    __syncthreads();

    float acc[4][NC] = {};
    #pragma unroll
    for (int kk = 0; kk < K; ++kk) {
        float4 a = *(const float4*)&sAT[kk][ty * 4];
        float av[4] = {a.x, a.y, a.z, a.w};
        float wv[NC];
        if constexpr (NC == 4) {
            float4 w = *(const float4*)&sW[kk][tx * 4];
            wv[0] = w.x; wv[1] = w.y; wv[2] = w.z; wv[3] = w.w;
        } else {
            float2 w = *(const float2*)&sW[kk][tx * 2];
            wv[0] = w.x; wv[1] = w.y;
        }
        #pragma unroll
        for (int i = 0; i < 4; ++i) {
            #pragma unroll
            for (int j = 0; j < NC; ++j)
                acc[i][j] = fmaf(av[i], wv[j], acc[i][j]);
        }
    }
    #pragma unroll
    for (int i = 0; i < 4; ++i) {
        int row = row0 + ty * 4 + i;
        if constexpr (NC == 4) {
            float4 v = {acc[i][0], acc[i][1], acc[i][2], acc[i][3]};
            *(float4*)(O + (size_t)row * N + tx * 4) = v;
        } else {
            float2 v = {acc[i][0], acc[i][1]};
            *(float2*)(O + (size_t)row * N + tx * 2) = v;
        }
    }
}

// ---------------- fused gather + norm + bias + relu ----------------
template<int N>
__global__ __launch_bounds__(256) void gather_combine(
    const float* __restrict__ m, const unsigned short* __restrict__ csr,
    const int* __restrict__ off, const int* __restrict__ cnt,
    const float* __restrict__ rdeg_i, const float* __restrict__ bias,
    float* __restrict__ outDrug, float* __restrict__ outDis) {
    constexpr int NPW = 64 / N;              // nodes per wave
    const int lane = threadIdx.x & 63;
    const int wave = threadIdx.x >> 6;
    const int sub = lane / N;
    const int f = lane % N;
    const int node = (blockIdx.x * 4 + wave) * NPW + sub;
    if (node >= N_NODE) return;
    const int typ = blockIdx.y;              // 0: drug (rel 0,2)  1: dis (rel 1,3)
    const int ra = (typ == 0) ? 0 : 1, rb = (typ == 0) ? 2 : 3;

    float acc[2] = {0.0f, 0.0f};
    const int rels[2] = {ra, rb};
    #pragma unroll
    for (int q = 0; q < 2; ++q) {
        const int rid = rels[q] * N_NODE + node;
        const int beg = off[rid];
        const int c = cnt[rid];
        const float* mr = m + (size_t)rels[q] * N_NODE * N;
        int k = 0;
        for (; k + 4 <= c; k += 4) {
            int s0 = csr[beg + k], s1 = csr[beg + k + 1];
            int s2 = csr[beg + k + 2], s3 = csr[beg + k + 3];
            float v0 = mr[s0 * N + f], v1 = mr[s1 * N + f];
            float v2 = mr[s2 * N + f], v3 = mr[s3 * N + f];
            acc[q] += (v0 + v1) + (v2 + v3);
        }
        for (; k < c; ++k) acc[q] += mr[csr[beg + k] * N + f];
    }
    float o = acc[0] * rdeg_i[ra * N_NODE + node] + acc[1] * rdeg_i[rb * N_NODE + node]
            + bias[ra * N + f] + bias[rb * N + f];
    o = fmaxf(o, 0.0f);
    (typ == 0 ? outDrug : outDis)[(size_t)node * N + f] = o;
}

// ---------------- final NT GEMM: C[M x Nc] = A[M x 32] @ B[Nc x 32]^T ----------------
__global__ __launch_bounds__(256) void gemm_nt_final(
    const float* __restrict__ A, const float* __restrict__ B,
    float* __restrict__ C, int M, int Nc) {
    __shared__ float sAT[32][132];
    __shared__ float sBT[32][68];
    const int tid = threadIdx.x;
    const int tx = tid & 15, ty = tid >> 4;
    const int row0 = blockIdx.x * 128, col0 = blockIdx.y * 64;
    #pragma unroll
    for (int i = 0; i < 4; ++i) {
        int f = tid + i * 256;
        int r = f >> 3, k4 = f & 7;
        int row = min(row0 + r, M - 1);
        const float4 v = *(const float4*)(A + (size_t)row * 32 + k4 * 4);
        sAT[k4 * 4 + 0][r] = v.x; sAT[k4 * 4 + 1][r] = v.y;
        sAT[k4 * 4 + 2][r] = v.z; sAT[k4 * 4 + 3][r] = v.w;
    }
    #pragma unroll
    for (int i = 0; i < 2; ++i) {
        int f = tid + i * 256;
        int br = f >> 3, k4 = f & 7;
        const float4 v = *(const float4*)(B + (size_t)(col0 + br) * 32 + k4 * 4);
        sBT[k4 * 4 + 0][br] = v.x; sBT[k4 * 4 + 1][br] = v.y;
        sBT[k4 * 4 + 2][br] = v.z; sBT[k4 * 4 + 3][br] = v.w;
    }
    __syncthreads();
    float acc[8][4] = {};
    #pragma unroll
    for (int a = 0; a < 32; ++a) {
        float4 a0 = *(const float4*)&sAT[a][ty * 8];
        float4 a1 = *(const float4*)&sAT[a][ty * 8 + 4];
        float4 b4 = *(const float4*)&sBT[a][tx * 4];
        float av[8] = {a0.x, a0.y, a0.z, a0.w, a1.x, a1.y, a1.z, a1.w};
        float bv[4] = {b4.x, b4.y, b4.z, b4.w};
        #pragma unroll
        for (int i = 0; i < 8; ++i) {
            #pragma unroll
            for (int j = 0; j < 4; ++j)
                acc[i][j] = fmaf(av[i], bv[j], acc[i][j]);
        }
    }
    #pragma unroll
    for (int i = 0; i < 8; ++i) {
        int row = row0 + ty * 8 + i;
        if (row < M) {
            float4 v = {acc[i][0], acc[i][1], acc[i][2], acc[i][3]};
            *(float4*)(C + (size_t)row * Nc + col0 + tx * 4) = v;
        }
    }
}

extern "C" void kernel_launch(void* const* d_in, const int* in_sizes, int n_in,
                              void* d_out, int out_size, void* d_ws, size_t ws_size,
                              hipStream_t stream) {
    const float* feat_drug = (const float*)d_in[0];
    const float* feat_dis  = (const float*)d_in[1];
    const float* W_drug    = (const float*)d_in[2];
    const float* W_dis     = (const float*)d_in[3];
    const float* W1        = (const float*)d_in[4];
    const float* b1        = (const float*)d_in[5];
    const float* W2        = (const float*)d_in[6];
    const float* b2        = (const float*)d_in[7];
    const float* Wf        = (const float*)d_in[8];
    const int*   src       = (const int*)d_in[9];
    const int*   dst       = (const int*)d_in[10];
    float* out = (float*)d_out;

    // ---- workspace carve: 20.32 MB (< 20.74 MB proven) ----
    float* fbase   = (float*)d_ws;
    float* rdeg_o  = fbase;                  // 32000
    float* rdeg_i  = fbase + 32000;          // 32000
    float* h_drug  = fbase + 64000;          // 8000*64
    float* h_dis   = fbase + 576000;         // 8000*64
    float* m       = fbase + 1088000;        // 4*8000*64
    float* h2_drug = fbase + 3136000;        // 8000*32
    float* h2_dis  = fbase + 3392000;        // 8000*32
    float* g       = fbase + 3648000;        // 8000*32  (floats end at 3,904,000)
    int*   ibase   = (int*)(fbase + 3904000);
    int*   cnt_o   = ibase;                  // 32000
    int*   cnt_i   = ibase + 32000;          // 32000
    int*   off     = ibase + 64000;          // 32000
    int*   cursor  = ibase + 96000;          // 32000
    unsigned short* csr = (unsigned short*)(ibase + 128000);   // 2,097,152 ushorts
    float* h1_drug = h_drug;                 // alias: h dead after L1 gemm_small
    float* h1_dis  = h_dis;                  // alias

    hipMemsetAsync(cnt_o, 0, 64000 * sizeof(int), stream);        // cnt_o + cnt_i
    hipMemsetAsync(h_drug, 0, 1024000 * sizeof(float), stream);   // split-K accumulators

    // ---- CSR build (dst-sorted, reused by both layers) ----
    count_kernel<<<8192, 256, 0, stream>>>(src, dst, cnt_o, cnt_i);
    rdeg_kernel<<<125, 256, 0, stream>>>(cnt_o, rdeg_o, 32000);
    rdeg_kernel<<<125, 256, 0, stream>>>(cnt_i, rdeg_i, 32000);
    scan_kernel<<<1, 1024, 0, stream>>>(cnt_i, off, cursor);
    place_kernel<<<8192, 256, 0, stream>>>(src, dst, cursor, csr);

    // ---- input embeddings: h = feat @ W (64-row tiles x 5-way split-K) ----
    dim3 ge(125, 5);
    embed_gemm<<<ge, 256, 0, stream>>>(feat_drug, W_drug, h_drug, N_NODE, 1600);
    embed_gemm<<<ge, 256, 0, stream>>>(feat_dis,  W_dis,  h_dis,  N_NODE, 1600);

    // ---- hetero layer 1 (64 -> 64) ----
    gemm_small<64, 64><<<dim3(125, 4), 256, 0, stream>>>(h_drug, h_dis, W1, rdeg_o, m, N_NODE);
    gather_combine<64><<<dim3(2000, 2), 256, 0, stream>>>(m, csr, off, cnt_i, rdeg_i, b1, h1_drug, h1_dis);

    // ---- hetero layer 2 (64 -> 32) ----
    gemm_small<64, 32><<<dim3(125, 4), 256, 0, stream>>>(h1_drug, h1_dis, W2, rdeg_o, m, N_NODE);
    gather_combine<32><<<dim3(1000, 2), 256, 0, stream>>>(m, csr, off, cnt_i, rdeg_i, b2, h2_drug, h2_dis);

    // ---- bilinear scoring: out = h2_drug @ (h2_dis @ Wf)^T ----
    gemm_small<32, 32><<<dim3(125, 1), 256, 0, stream>>>(h2_dis, h2_dis, Wf, nullptr, g, N_NODE);
    gemm_nt_final<<<dim3(63, 125), 256, 0, stream>>>(h2_drug, g, out, N_NODE, N_NODE);
}

// Round 8
// 1204.365 us; speedup vs baseline: 3.1816x; 1.0402x over previous
//
#include <hip/hip_runtime.h>
#include <hip/hip_bf16.h>

#define N_NODE 8000
#define EDGES  524288   // 2^19 per relation
#define LOG2E  19
#define NREL   4
#define CB     16       // count-partial blocks per relation

// ---------------- count: LDS-privatized histograms, no global atomics ----------------
__global__ __launch_bounds__(256) void count_part_kernel(
    const int* __restrict__ src, const int* __restrict__ dst,
    int* __restrict__ part /* [NREL*CB][16000] */) {
    __shared__ int ho[N_NODE];   // 32 KB
    __shared__ int hi[N_NODE];   // 32 KB
    const int r = blockIdx.y, b = blockIdx.x;
    for (int i = threadIdx.x; i < N_NODE; i += 256) { ho[i] = 0; hi[i] = 0; }
    __syncthreads();
    const int base = r * EDGES + b * (EDGES / CB);
    for (int k = threadIdx.x; k < EDGES / CB; k += 256) {
        atomicAdd(&ho[src[base + k]], 1);   // LDS atomics
        atomicAdd(&hi[dst[base + k]], 1);
    }
    __syncthreads();
    int* po = part + (size_t)(r * CB + b) * 16000;
    for (int i = threadIdx.x; i < N_NODE; i += 256) {
        po[i] = ho[i];
        po[8000 + i] = hi[i];
    }
}

__global__ void count_reduce_kernel(const int* __restrict__ part,
                                    int* __restrict__ cnt_o, int* __restrict__ cnt_i) {
    int t = blockIdx.x * blockDim.x + threadIdx.x;
    if (t >= NREL * N_NODE) return;
    int r = t / N_NODE, i = t - r * N_NODE;
    const int* p = part + (size_t)r * CB * 16000;
    int so = 0, si = 0;
    #pragma unroll
    for (int b = 0; b < CB; ++b) {
        so += p[b * 16000 + i];
        si += p[b * 16000 + 8000 + i];
    }
    cnt_o[t] = so;
    cnt_i[t] = si;
}

__global__ void rdeg_kernel(const int* __restrict__ cnt, float* __restrict__ rdeg, int n) {
    int t = blockIdx.x * blockDim.x + threadIdx.x;
    if (t < n) rdeg[t] = rsqrtf((float)max(cnt[t], 1));
}

// exclusive prefix sum over 32000 counters; single block of 1024, 32 chunks.
__global__ __launch_bounds__(1024) void scan_kernel(const int* __restrict__ cnt,
                                                    int* __restrict__ off, int* __restrict__ cursor) {
    __shared__ int buf[1024];
    __shared__ int sbase;
    if (threadIdx.x == 0) sbase = 0;
    __syncthreads();
    for (int c = 0; c < 32; ++c) {
        int i = c * 1024 + threadIdx.x;
        int v = (i < NREL * N_NODE) ? cnt[i] : 0;
        buf[threadIdx.x] = v;
        __syncthreads();
        for (int s = 1; s < 1024; s <<= 1) {
            int t = (threadIdx.x >= s) ? buf[threadIdx.x - s] : 0;
            __syncthreads();
            buf[threadIdx.x] += t;
            __syncthreads();
        }
        int b = sbase;
        if (i < NREL * N_NODE) {
            int excl = b + buf[threadIdx.x] - v;
            off[i] = excl;
            cursor[i] = excl;
        }
        __syncthreads();
        if (threadIdx.x == 1023) sbase = b + buf[1023];
        __syncthreads();
    }
}

__global__ void place_kernel(const int* __restrict__ src, const int* __restrict__ dst,
                             int* __restrict__ cursor, unsigned short* __restrict__ csr) {
    int t = blockIdx.x * blockDim.x + threadIdx.x;
    if (t >= NREL * EDGES) return;
    int r = t >> LOG2E;
    int pos = atomicAdd(&cursor[r * N_NODE + dst[t]], 1);
    csr[pos] = (unsigned short)src[t];
}

// ---------------- embed GEMM: C[8000 x 64] += A[8000 x 8000] @ W[8000 x 64] ----------------
// 64-row tiles, 5-way split-K (1600 k), register-prefetch, row-major A in LDS, 4x4 thread tile.
__global__ __launch_bounds__(256) void embed_gemm(
    const float* __restrict__ A, const float* __restrict__ W,
    float* __restrict__ C, int K, int k_per_split) {
    __shared__ float sA[64][36];
    __shared__ float sW[32][68];
    const int tid = threadIdx.x;
    const int tx = tid & 15, ty = tid >> 4;
    const int row0 = blockIdx.x * 64;
    const int kb = blockIdx.y * k_per_split;
    const int nt = k_per_split / 32;

    const int ar = tid >> 3, ak4 = tid & 7;
    const int wk = tid >> 4, wc4 = tid & 15;
    const float* Ap0 = A + (size_t)(row0 + ar) * K + ak4 * 4;
    const float* Ap1 = A + (size_t)(row0 + ar + 32) * K + ak4 * 4;
    const float* Wp0 = W + (size_t)wk * 64 + wc4 * 4;
    const float* Wp1 = W + (size_t)(wk + 16) * 64 + wc4 * 4;

    float4 pa0, pa1, pw0, pw1;
    pa0 = *(const float4*)(Ap0 + kb);
    pa1 = *(const float4*)(Ap1 + kb);
    pw0 = *(const float4*)(Wp0 + (size_t)kb * 64);
    pw1 = *(const float4*)(Wp1 + (size_t)kb * 64);

    float acc[4][4] = {};

    for (int t = 0; t < nt; ++t) {
        *(float4*)&sA[ar][ak4 * 4] = pa0;
        *(float4*)&sA[ar + 32][ak4 * 4] = pa1;
        *(float4*)&sW[wk][wc4 * 4] = pw0;
        *(float4*)&sW[wk + 16][wc4 * 4] = pw1;
        __syncthreads();
        if (t + 1 < nt) {
            int kk0 = kb + (t + 1) * 32;
            pa0 = *(const float4*)(Ap0 + kk0);
            pa1 = *(const float4*)(Ap1 + kk0);
            pw0 = *(const float4*)(Wp0 + (size_t)kk0 * 64);
            pw1 = *(const float4*)(Wp1 + (size_t)kk0 * 64);
        }
        #pragma unroll
        for (int q = 0; q < 8; ++q) {
            float4 a0 = *(const float4*)&sA[ty * 4 + 0][q * 4];
            float4 a1 = *(const float4*)&sA[ty * 4 + 1][q * 4];
            float4 a2 = *(const float4*)&sA[ty * 4 + 2][q * 4];
            float4 a3 = *(const float4*)&sA[ty * 4 + 3][q * 4];
            float4 w0 = *(const float4*)&sW[q * 4 + 0][tx * 4];
            float4 w1 = *(const float4*)&sW[q * 4 + 1][tx * 4];
            float4 w2 = *(const float4*)&sW[q * 4 + 2][tx * 4];
            float4 w3 = *(const float4*)&sW[q * 4 + 3][tx * 4];
            float av[4][4] = {{a0.x, a0.y, a0.z, a0.w}, {a1.x, a1.y, a1.z, a1.w},
                              {a2.x, a2.y, a2.z, a2.w}, {a3.x, a3.y, a3.z, a3.w}};
            float wv[4][4] = {{w0.x, w0.y, w0.z, w0.w}, {w1.x, w1.y, w1.z, w1.w},
                              {w2.x, w2.y, w2.z, w2.w}, {w3.x, w3.y, w3.z, w3.w}};
            #pragma unroll
            for (int i = 0; i < 4; ++i) {
                #pragma unroll
                for (int j = 0; j < 4; ++j) {
                    #pragma unroll
                    for (int kk = 0; kk < 4; ++kk)
                        acc[i][j] = fmaf(av[i][kk], wv[kk][j], acc[i][j]);
                }
            }
        }
        __syncthreads();
    }
    #pragma unroll
    for (int i = 0; i < 4; ++i) {
        float* cp = &C[(size_t)(row0 + ty * 4 + i) * 64 + tx * 4];
        #pragma unroll
        for (int j = 0; j < 4; ++j)
            atomicAdd(cp + j, acc[i][j]);
    }
}

// ---------------- small GEMM: out[r] = diag(scale[r]) * A_r [M x K] @ W[r] [K x N] ----------------
template<int K, int N>
__global__ __launch_bounds__(256) void gemm_small(
    const float* __restrict__ Adrug, const float* __restrict__ Adis,
    const float* __restrict__ Wall, const float* __restrict__ scaleAll,
    float* __restrict__ outAll, int M) {
    const int r = blockIdx.y;
    const float* A = (r < 2) ? Adrug : Adis;
    const float* W = Wall + (size_t)r * K * N;
    const float* scale = scaleAll ? (scaleAll + (size_t)r * N_NODE) : nullptr;
    float* O = outAll + (size_t)r * M * N;

    __shared__ float sAT[K][68];
    __shared__ float sW[K][N + 4];
    const int tid = threadIdx.x;
    const int tx = tid & 15, ty = tid >> 4;
    const int row0 = blockIdx.x * 64;
    constexpr int NC = N / 16;

    constexpr int AF4 = 64 * K / 4 / 256;
    #pragma unroll
    for (int i = 0; i < AF4; ++i) {
        int f = tid + i * 256;
        int rr = f / (K / 4), k4 = f % (K / 4);
        int row = row0 + rr;
        float s = scale ? scale[row] : 1.0f;
        const float4 v = *(const float4*)(A + (size_t)row * K + k4 * 4);
        sAT[k4 * 4 + 0][rr] = v.x * s; sAT[k4 * 4 + 1][rr] = v.y * s;
        sAT[k4 * 4 + 2][rr] = v.z * s; sAT[k4 * 4 + 3][rr] = v.w * s;
    }
    constexpr int WF4 = K * N / 4 / 256;
    #pragma unroll
    for (int i = 0; i < WF4; ++i) {
        int f = tid + i * 256;
        int kr = f / (N / 4), c4 = f % (N / 4);
        *(float4*)&sW[kr][c4 * 4] = *(const float4*)(W + (size_t)kr * N + c4 * 4);
    }
    __syncthreads();

    float acc[4][NC] = {};
    #pragma unroll
    for (int kk = 0; kk < K; ++kk) {
        float4 a = *(const float4*)&sAT[kk][ty * 4];
        float av[4] = {a.x, a.y, a.z, a.w};
        float wv[NC];
        if constexpr (NC == 4) {
            float4 w = *(const float4*)&sW[kk][tx * 4];
            wv[0] = w.x; wv[1] = w.y; wv[2] = w.z; wv[3] = w.w;
        } else {
            float2 w = *(const float2*)&sW[kk][tx * 2];
            wv[0] = w.x; wv[1] = w.y;
        }
        #pragma unroll
        for (int i = 0; i < 4; ++i) {
            #pragma unroll
            for (int j = 0; j < NC; ++j)
                acc[i][j] = fmaf(av[i], wv[j], acc[i][j]);
        }
    }
    #pragma unroll
    for (int i = 0; i < 4; ++i) {
        int row = row0 + ty * 4 + i;
        if constexpr (NC == 4) {
            float4 v = {acc[i][0], acc[i][1], acc[i][2], acc[i][3]};
            *(float4*)(O + (size_t)row * N + tx * 4) = v;
        } else {
            float2 v = {acc[i][0], acc[i][1]};
            *(float2*)(O + (size_t)row * N + tx * 2) = v;
        }
    }
}

// ---------------- fused gather + norm + bias + relu ----------------
template<int N>
__global__ __launch_bounds__(256) void gather_combine(
    const float* __restrict__ m, const unsigned short* __restrict__ csr,
    const int* __restrict__ off, const int* __restrict__ cnt,
    const float* __restrict__ rdeg_i, const float* __restrict__ bias,
    float* __restrict__ outDrug, float* __restrict__ outDis) {
    constexpr int NPW = 64 / N;              // nodes per wave
    const int lane = threadIdx.x & 63;
    const int wave = threadIdx.x >> 6;
    const int sub = lane / N;
    const int f = lane % N;
    const int node = (blockIdx.x * 4 + wave) * NPW + sub;
    if (node >= N_NODE) return;
    const int typ = blockIdx.y;              // 0: drug (rel 0,2)  1: dis (rel 1,3)
    const int ra = (typ == 0) ? 0 : 1, rb = (typ == 0) ? 2 : 3;

    float acc[2] = {0.0f, 0.0f};
    const int rels[2] = {ra, rb};
    #pragma unroll
    for (int q = 0; q < 2; ++q) {
        const int rid = rels[q] * N_NODE + node;
        const int beg = off[rid];
        const int c = cnt[rid];
        const float* mr = m + (size_t)rels[q] * N_NODE * N;
        int k = 0;
        for (; k + 4 <= c; k += 4) {
            int s0 = csr[beg + k], s1 = csr[beg + k + 1];
            int s2 = csr[beg + k + 2], s3 = csr[beg + k + 3];
            float v0 = mr[s0 * N + f], v1 = mr[s1 * N + f];
            float v2 = mr[s2 * N + f], v3 = mr[s3 * N + f];
            acc[q] += (v0 + v1) + (v2 + v3);
        }
        for (; k < c; ++k) acc[q] += mr[csr[beg + k] * N + f];
    }
    float o = acc[0] * rdeg_i[ra * N_NODE + node] + acc[1] * rdeg_i[rb * N_NODE + node]
            + bias[ra * N + f] + bias[rb * N + f];
    o = fmaxf(o, 0.0f);
    (typ == 0 ? outDrug : outDis)[(size_t)node * N + f] = o;
}

// ---------------- final NT GEMM: C[M x Nc] = A[M x 32] @ B[Nc x 32]^T ----------------
__global__ __launch_bounds__(256) void gemm_nt_final(
    const float* __restrict__ A, const float* __restrict__ B,
    float* __restrict__ C, int M, int Nc) {
    __shared__ float sAT[32][132];
    __shared__ float sBT[32][68];
    const int tid = threadIdx.x;
    const int tx = tid & 15, ty = tid >> 4;
    const int row0 = blockIdx.x * 128, col0 = blockIdx.y * 64;
    #pragma unroll
    for (int i = 0; i < 4; ++i) {
        int f = tid + i * 256;
        int r = f >> 3, k4 = f & 7;
        int row = min(row0 + r, M - 1);
        const float4 v = *(const float4*)(A + (size_t)row * 32 + k4 * 4);
        sAT[k4 * 4 + 0][r] = v.x; sAT[k4 * 4 + 1][r] = v.y;
        sAT[k4 * 4 + 2][r] = v.z; sAT[k4 * 4 + 3][r] = v.w;
    }
    #pragma unroll
    for (int i = 0; i < 2; ++i) {
        int f = tid + i * 256;
        int br = f >> 3, k4 = f & 7;
        const float4 v = *(const float4*)(B + (size_t)(col0 + br) * 32 + k4 * 4);
        sBT[k4 * 4 + 0][br] = v.x; sBT[k4 * 4 + 1][br] = v.y;
        sBT[k4 * 4 + 2][br] = v.z; sBT[k4 * 4 + 3][br] = v.w;
    }
    __syncthreads();
    float acc[8][4] = {};
    #pragma unroll
    for (int a = 0; a < 32; ++a) {
        float4 a0 = *(const float4*)&sAT[a][ty * 8];
        float4 a1 = *(const float4*)&sAT[a][ty * 8 + 4];
        float4 b4 = *(const float4*)&sBT[a][tx * 4];
        float av[8] = {a0.x, a0.y, a0.z, a0.w, a1.x, a1.y, a1.z, a1.w};
        float bv[4] = {b4.x, b4.y, b4.z, b4.w};
        #pragma unroll
        for (int i = 0; i < 8; ++i) {
            #pragma unroll
            for (int j = 0; j < 4; ++j)
                acc[i][j] = fmaf(av[i], bv[j], acc[i][j]);
        }
    }
    #pragma unroll
    for (int i = 0; i < 8; ++i) {
        int row = row0 + ty * 8 + i;
        if (row < M) {
            float4 v = {acc[i][0], acc[i][1], acc[i][2], acc[i][3]};
            *(float4*)(C + (size_t)row * Nc + col0 + tx * 4) = v;
        }
    }
}

extern "C" void kernel_launch(void* const* d_in, const int* in_sizes, int n_in,
                              void* d_out, int out_size, void* d_ws, size_t ws_size,
                              hipStream_t stream) {
    const float* feat_drug = (const float*)d_in[0];
    const float* feat_dis  = (const float*)d_in[1];
    const float* W_drug    = (const float*)d_in[2];
    const float* W_dis     = (const float*)d_in[3];
    const float* W1        = (const float*)d_in[4];
    const float* b1        = (const float*)d_in[5];
    const float* W2        = (const float*)d_in[6];
    const float* b2        = (const float*)d_in[7];
    const float* Wf        = (const float*)d_in[8];
    const int*   src       = (const int*)d_in[9];
    const int*   dst       = (const int*)d_in[10];
    float* out = (float*)d_out;

    // ---- workspace carve: 20.32 MB (< 20.74 MB proven) ----
    float* fbase   = (float*)d_ws;
    float* rdeg_o  = fbase;                  // 32000
    float* rdeg_i  = fbase + 32000;          // 32000
    float* h_drug  = fbase + 64000;          // 8000*64
    float* h_dis   = fbase + 576000;         // 8000*64
    float* m       = fbase + 1088000;        // 4*8000*64
    float* h2_drug = fbase + 3136000;        // 8000*32
    float* h2_dis  = fbase + 3392000;        // 8000*32
    float* g       = fbase + 3648000;        // 8000*32  (floats end at 3,904,000)
    int*   ibase   = (int*)(fbase + 3904000);
    int*   cnt_o   = ibase;                  // 32000
    int*   cnt_i   = ibase + 32000;          // 32000
    int*   off     = ibase + 64000;          // 32000
    int*   cursor  = ibase + 96000;          // 32000
    unsigned short* csr = (unsigned short*)(ibase + 128000);   // 2,097,152 ushorts
    float* h1_drug = h_drug;                 // alias: h dead after L1 gemm_small
    float* h1_dis  = h_dis;                  // alias
    int*   part    = (int*)m;                // alias: 64*16000 ints = 4.1 MB in m's 8.2 MB
                                             // (m first written by gemm_small L1, after CSR build)

    hipMemsetAsync(h_drug, 0, 1024000 * sizeof(float), stream);   // split-K accumulators

    // ---- CSR build (dst-sorted, reused by both layers) ----
    count_part_kernel<<<dim3(CB, NREL), 256, 0, stream>>>(src, dst, part);
    count_reduce_kernel<<<125, 256, 0, stream>>>(part, cnt_o, cnt_i);
    rdeg_kernel<<<125, 256, 0, stream>>>(cnt_o, rdeg_o, 32000);
    rdeg_kernel<<<125, 256, 0, stream>>>(cnt_i, rdeg_i, 32000);
    scan_kernel<<<1, 1024, 0, stream>>>(cnt_i, off, cursor);
    place_kernel<<<8192, 256, 0, stream>>>(src, dst, cursor, csr);

    // ---- input embeddings: h = feat @ W (64-row tiles x 5-way split-K) ----
    dim3 ge(125, 5);
    embed_gemm<<<ge, 256, 0, stream>>>(feat_drug, W_drug, h_drug, N_NODE, 1600);
    embed_gemm<<<ge, 256, 0, stream>>>(feat_dis,  W_dis,  h_dis,  N_NODE, 1600);

    // ---- hetero layer 1 (64 -> 64) ----
    gemm_small<64, 64><<<dim3(125, 4), 256, 0, stream>>>(h_drug, h_dis, W1, rdeg_o, m, N_NODE);
    gather_combine<64><<<dim3(2000, 2), 256, 0, stream>>>(m, csr, off, cnt_i, rdeg_i, b1, h1_drug, h1_dis);

    // ---- hetero layer 2 (64 -> 32) ----
    gemm_small<64, 32><<<dim3(125, 4), 256, 0, stream>>>(h1_drug, h1_dis, W2, rdeg_o, m, N_NODE);
    gather_combine<32><<<dim3(1000, 2), 256, 0, stream>>>(m, csr, off, cnt_i, rdeg_i, b2, h2_drug, h2_dis);

    // ---- bilinear scoring: out = h2_drug @ (h2_dis @ Wf)^T ----
    gemm_small<32, 32><<<dim3(125, 1), 256, 0, stream>>>(h2_dis, h2_dis, Wf, nullptr, g, N_NODE);
    gemm_nt_final<<<dim3(63, 125), 256, 0, stream>>>(h2_drug, g, out, N_NODE, N_NODE);
}